// Round 19
// baseline (436.304 us; speedup 1.0000x reference)
//
#include <hip/hip_runtime.h>
#include <hip/hip_bf16.h>
#include <cstdint>

#define NB 8
#define NN 3072
#define HD 64
#define KK 16
#define NL 2
#define ROWS_TOT (NB * NN)

typedef unsigned long long u64;
typedef __attribute__((ext_vector_type(8))) short short8;
typedef __attribute__((ext_vector_type(4))) float f32x4;

__device__ __forceinline__ float elu_f(float x) {
  return x > 0.0f ? x : __expf(x) - 1.0f;  // v_exp-based; abs err ~1e-7
}

__device__ __forceinline__ unsigned sortkey(float f) {
  unsigned u = __float_as_uint(f);
  unsigned m = ((unsigned)((int)u >> 31)) | 0x80000000u;
  return u ^ m;  // monotone float->uint map
}

// packed RNE f32->bf16 pair: returns lo16 = bf16(a), hi16 = bf16(b).
__device__ __forceinline__ unsigned pk2(float a, float b) {
  __hip_bfloat162 v = __float22bfloat162_rn(make_float2(a, b));
  return *(unsigned*)&v;
}

__device__ __forceinline__ unsigned short bf16rne(float f) {
  unsigned u = __float_as_uint(f);
  return (unsigned short)((u + 0x7fffu + ((u >> 16) & 1u)) >> 16);
}

// async global->LDS, 16B per lane; LDS dest must be wave-uniform base + lane*16
__device__ __forceinline__ void gl_lds16(const void* g, void* l) {
  __builtin_amdgcn_global_load_lds(
      (const __attribute__((address_space(1))) unsigned int*)g,
      (__attribute__((address_space(3))) unsigned int*)l, 16, 0, 0);
}

// ---- fused embed + split + norms (layer 0) ----
__global__ void k_embed2(const float* __restrict__ x, const float* __restrict__ dn,
                         const float* __restrict__ Win, const float* __restrict__ bin,
                         float* __restrict__ h, unsigned short* __restrict__ hhi,
                         unsigned short* __restrict__ hlo, float* __restrict__ xx) {
  __shared__ float xsum[32];
  const int t = threadIdx.x;
  const int C = blockIdx.x * 256 + t;  // one 8-elem chunk per thread
  const int Rg = C >> 10;
  const int within = C & 1023;
  const int rt16 = within >> 7;
  const int kc = (within >> 6) & 1;
  const int quad = (within >> 4) & 3;
  const int row = within & 15;
  const int lr = ((t >> 7) & 1) * 16 + (t & 15);  // local row 0..31
  const int r = Rg * 128 + rt16 * 16 + row;
  const int k0 = kc * 32 + quad * 8;
  if (t < 32) xsum[t] = 0.0f;
  __syncthreads();
  const float xd0 = x[(size_t)r * 3 + 0] * dn[0];
  const float xd1 = x[(size_t)r * 3 + 1] * dn[1];
  const float xd2 = x[(size_t)r * 3 + 2] * dn[2];
  float hv[8];
  float ss = 0.0f;
#pragma unroll
  for (int j = 0; j < 8; ++j) {
    const int d = k0 + j;
    float a = bin[d];
    a = fmaf(xd0, Win[d], a);
    a = fmaf(xd1, Win[HD + d], a);
    a = fmaf(xd2, Win[2 * HD + d], a);
    const float f = elu_f(a);
    hv[j] = f;
    ss = fmaf(f, f, ss);
  }
  atomicAdd(&xsum[lr], ss);
  *(float4*)(h + (size_t)r * HD + k0) = (float4){hv[0], hv[1], hv[2], hv[3]};
  *(float4*)(h + (size_t)r * HD + k0 + 4) = (float4){hv[4], hv[5], hv[6], hv[7]};
  uint4 oh, ol;
  unsigned* ohv = (unsigned*)&oh;
  unsigned* olv = (unsigned*)&ol;
#pragma unroll
  for (int jp = 0; jp < 4; ++jp) {
    const float f0 = hv[2 * jp], f1 = hv[2 * jp + 1];
    const unsigned hi = pk2(f0, f1);
    ohv[jp] = hi;
    const float hif0 = __uint_as_float(hi << 16);
    const float hif1 = __uint_as_float(hi & 0xffff0000u);
    olv[jp] = pk2(f0 - hif0, f1 - hif1);
  }
  *(uint4*)(hhi + (size_t)C * 8) = oh;
  *(uint4*)(hlo + (size_t)C * 8) = ol;
  __syncthreads();
  if (((t >> 4) & 7) == 0) xx[r] = xsum[lr];
}

// ------- split h (fp32) -> bf16 hi/lo in MFMA fragment order; fused row norms ----
__global__ void k_split(const float* __restrict__ h, unsigned short* __restrict__ hhi,
                        unsigned short* __restrict__ hlo, float* __restrict__ xx) {
  __shared__ float xsum[32];
  const int t = threadIdx.x;
  const int C = blockIdx.x * 256 + t;  // one 8-elem chunk per thread
  const int Rg = C >> 10;              // 128-row block index
  const int within = C & 1023;
  const int rt16 = within >> 7;
  const int kc = (within >> 6) & 1;
  const int quad = (within >> 4) & 3;
  const int row = within & 15;
  const int lr = ((t >> 7) & 1) * 16 + (t & 15);  // local row 0..31
  const int r = Rg * 128 + rt16 * 16 + row;
  const int k0 = kc * 32 + quad * 8;
  const float* src = h + (size_t)r * HD + k0;
  if (t < 32) xsum[t] = 0.0f;
  __syncthreads();
  const float4 v0 = *(const float4*)src;
  const float4 v1 = *(const float4*)(src + 4);
  const float fv[8] = {v0.x, v0.y, v0.z, v0.w, v1.x, v1.y, v1.z, v1.w};
  float ss = 0.0f;
#pragma unroll
  for (int j = 0; j < 8; ++j) ss = fmaf(fv[j], fv[j], ss);
  atomicAdd(&xsum[lr], ss);
  uint4 oh, ol;
  unsigned* ohv = (unsigned*)&oh;
  unsigned* olv = (unsigned*)&ol;
#pragma unroll
  for (int jp = 0; jp < 4; ++jp) {
    const float f0 = fv[2 * jp], f1 = fv[2 * jp + 1];
    const unsigned hi = pk2(f0, f1);
    ohv[jp] = hi;
    const float hif0 = __uint_as_float(hi << 16);
    const float hif1 = __uint_as_float(hi & 0xffff0000u);
    olv[jp] = pk2(f0 - hif0, f1 - hif1);
  }
  *(uint4*)(hhi + (size_t)C * 8) = oh;
  *(uint4*)(hlo + (size_t)C * 8) = ol;
  __syncthreads();
  if (((t >> 4) & 7) == 0) xx[r] = xsum[lr];  // kc==0 && quad==0: 32 writers
}

// ---- pack weights into MFMA B-fragment order: W1[0:64] hi+lo, W1[64:128] hi, W2 hi
__global__ void k_packw(const float* __restrict__ W1, const float* __restrict__ W2,
                        unsigned short* __restrict__ w0h, unsigned short* __restrict__ w0l,
                        unsigned short* __restrict__ w1h, unsigned short* __restrict__ w2h) {
  const int cid = blockIdx.x * 256 + threadIdx.x;  // 6144 chunks
  const int l = cid / 3072;
  const int r = cid % 3072;
  const int lane = r & 63;
  if (r < 1024) {  // W1 base part (K=0..63), hi+lo
    const int c = r;
    const int nt = c >> 7, kc = (c >> 6) & 1;
    const int k0 = kc * 32 + (lane >> 4) * 8;
    const int n = nt * 16 + (lane & 15);
    unsigned short* dh = w0h + ((size_t)l * 1024 + c) * 8;
    unsigned short* dl = w0l + ((size_t)l * 1024 + c) * 8;
#pragma unroll
    for (int j = 0; j < 8; ++j) {
      const float f = W1[(size_t)l * 16384 + (k0 + j) * 128 + n];
      const unsigned short hb = bf16rne(f);
      const float lo = f - __uint_as_float((unsigned)hb << 16);
      dh[j] = hb;
      dl[j] = bf16rne(lo);
    }
  } else if (r < 2048) {  // W1 diff part (K=64..127), hi only
    const int c = r - 1024;
    const int nt = c >> 7, kc = (c >> 6) & 1;
    const int k0 = 64 + kc * 32 + (lane >> 4) * 8;
    const int n = nt * 16 + (lane & 15);
    unsigned short* dh = w1h + ((size_t)l * 1024 + c) * 8;
#pragma unroll
    for (int j = 0; j < 8; ++j) dh[j] = bf16rne(W1[(size_t)l * 16384 + (k0 + j) * 128 + n]);
  } else {  // W2, hi only
    const int c = r - 2048;
    const int nt = c >> 8, kc = (c >> 6) & 3;
    const int k0 = kc * 32 + (lane >> 4) * 8;
    const int n = nt * 16 + (lane & 15);
    unsigned short* dh = w2h + ((size_t)l * 1024 + c) * 8;
#pragma unroll
    for (int j = 0; j < 8; ++j) dh[j] = bf16rne(W2[(size_t)l * 8192 + (k0 + j) * 64 + n]);
  }
}

// ---------------- KNN stage A: per-(tile,row) min of d2' -------------------------
__global__ __launch_bounds__(256) void k_stat(const unsigned short* __restrict__ hhi,
                                              const unsigned short* __restrict__ hlo,
                                              const float* __restrict__ xx,
                                              float* __restrict__ tilemin) {
  __shared__ __align__(16) unsigned short Bh[2][4096], Bl[2][4096];  // 32 KB
  __shared__ float smin[128 * 13];                                   // 6.7 KB
  const int t = threadIdx.x;
  const int bg = blockIdx.x / 96;
  const int rem = blockIdx.x % 96;
  const int qg = rem / 4, cq = rem % 4;
  const int w = t >> 6, lane = t & 63;
  const int lane16 = lane & 15, quad = lane >> 4;
  const float* xxb = xx + (size_t)bg * NN;

  short8 afh[2][2], afl[2][2];  // 2 mt x 2 kc; rows qg*128 + w*32 + mt*16 + ...
  {
    const size_t base = ((size_t)bg * 24 + qg) * 8192;
#pragma unroll
    for (int mt = 0; mt < 2; ++mt)
#pragma unroll
      for (int kc = 0; kc < 2; ++kc) {
        const size_t off = base + (size_t)(w * 2 + mt) * 1024 + kc * 512 + lane * 8;
        afh[mt][kc] = *(const short8*)(hhi + off);
        afl[mt][kc] = *(const short8*)(hlo + off);
      }
  }
#define STAGE(cb, bsel)                                                       \
  {                                                                           \
    const size_t bb = ((size_t)bg * 24 + ((cb) >> 1)) * 8192 +                \
                      (size_t)((cb) & 1) * 4096;                              \
    const char* sH = (const char*)(hhi + bb);                                 \
    const char* sL = (const char*)(hlo + bb);                                 \
    char* dH = (char*)&Bh[bsel][0];                                           \
    char* dL = (char*)&Bl[bsel][0];                                           \
    const int o1 = t * 16, o2 = t * 16 + 4096;                                \
    gl_lds16(sH + o1, dH + o1);                                               \
    gl_lds16(sH + o2, dH + o2);                                               \
    gl_lds16(sL + o1, dL + o1);                                               \
    gl_lds16(sL + o2, dL + o2);                                               \
  }

  STAGE(cq * 12, 0);
  __syncthreads();
  for (int it = 0; it < 12; ++it) {
    const int cb = cq * 12 + it;
    if (it + 1 < 12) STAGE(cb + 1, (it + 1) & 1);
    const unsigned short* bhp = Bh[it & 1];
    const unsigned short* blp = Bl[it & 1];
    f32x4 acc[2][4];
#pragma unroll
    for (int mt = 0; mt < 2; ++mt)
#pragma unroll
      for (int nt = 0; nt < 4; ++nt) acc[mt][nt] = (f32x4){0.f, 0.f, 0.f, 0.f};
#pragma unroll
    for (int kc = 0; kc < 2; ++kc)
#pragma unroll
      for (int nt = 0; nt < 4; ++nt) {
        const int off = nt * 1024 + kc * 512 + lane * 8;
        const short8 bh = *(const short8*)&bhp[off];
        const short8 bl = *(const short8*)&blp[off];
#pragma unroll
        for (int mt = 0; mt < 2; ++mt) {
          acc[mt][nt] = __builtin_amdgcn_mfma_f32_16x16x32_bf16(afh[mt][kc], bh, acc[mt][nt], 0, 0, 0);
          acc[mt][nt] = __builtin_amdgcn_mfma_f32_16x16x32_bf16(afh[mt][kc], bl, acc[mt][nt], 0, 0, 0);
          acc[mt][nt] = __builtin_amdgcn_mfma_f32_16x16x32_bf16(afl[mt][kc], bh, acc[mt][nt], 0, 0, 0);
        }
      }
    float rm[2][4];
#pragma unroll
    for (int mt = 0; mt < 2; ++mt)
#pragma unroll
      for (int r = 0; r < 4; ++r) rm[mt][r] = 3.402823466e+38f;
#pragma unroll
    for (int nt = 0; nt < 4; ++nt) {
      const float xc = xxb[cb * 64 + nt * 16 + lane16];
#pragma unroll
      for (int mt = 0; mt < 2; ++mt)
#pragma unroll
        for (int r = 0; r < 4; ++r)
          rm[mt][r] = fminf(rm[mt][r], fmaf(-2.0f, acc[mt][nt][r], xc));
    }
#pragma unroll
    for (int mask = 1; mask <= 8; mask <<= 1)
#pragma unroll
      for (int mt = 0; mt < 2; ++mt)
#pragma unroll
        for (int r = 0; r < 4; ++r)
          rm[mt][r] = fminf(rm[mt][r], __shfl_xor(rm[mt][r], mask, 64));
#pragma unroll
    for (int mt = 0; mt < 2; ++mt) {
      float v = rm[mt][0];
      v = (lane16 == 1) ? rm[mt][1] : v;
      v = (lane16 == 2) ? rm[mt][2] : v;
      v = (lane16 == 3) ? rm[mt][3] : v;
      if (lane16 < 4) {
        const int row = w * 32 + mt * 16 + quad * 4 + lane16;
        smin[row * 13 + it] = v;
      }
    }
    __syncthreads();  // drains prefetch vmcnt + syncs buffer reuse
  }
  // coalesced write: each of 128 rows writes its 12 contiguous floats
  if (t < 128) {
    float* dst = tilemin + ((size_t)bg * NN + qg * 128 + t) * 48 + cq * 12;
    const float* src = &smin[t * 13];
    *(float4*)dst = (float4){src[0], src[1], src[2], src[3]};
    *(float4*)(dst + 4) = (float4){src[4], src[5], src[6], src[7]};
    *(float4*)(dst + 8) = (float4){src[8], src[9], src[10], src[11]};
  }
}

// ---------------- KNN stage B: T[row] = 16th-smallest of 48 tile-mins ------------
__global__ __launch_bounds__(256) void k_thresh(const float* __restrict__ tilemin,
                                                float* __restrict__ T,
                                                int* __restrict__ cnt) {
  __shared__ float sb[4][64];
  const int t = threadIdx.x, w = t >> 6, lane = t & 63;
  const int row = blockIdx.x * 4 + w;
  const float v = (lane < 48) ? tilemin[(size_t)row * 48 + lane] : 3.402823466e+38f;
  sb[w][lane] = v;  // same-wave LDS: ordered
  int rank = 0;
  for (int i = 0; i < 48; ++i) {
    const float s = sb[w][i];
    rank += (s < v) || (s == v && i < lane);
  }
  if (lane < 48 && rank == 15) T[row] = v;
  if (lane == 0) cnt[row] = 0;
}

// ----- KNN stage C: recompute (bit-identical), LDS-compact survivors; cq==0 blocks
// also compute base1 = h @ W1[0:64] + b1 in the epilogue (A-frags already resident,
// identical fragment inputs & MFMA order as the old k_base => bit-identical).
__global__ __launch_bounds__(256) void k_compact(const unsigned short* __restrict__ hhi,
                                                 const unsigned short* __restrict__ hlo,
                                                 const float* __restrict__ xx,
                                                 const float* __restrict__ T,
                                                 int* __restrict__ cnt,
                                                 u64* __restrict__ surv,
                                                 const unsigned short* __restrict__ w0h,
                                                 const unsigned short* __restrict__ w0l,
                                                 const float* __restrict__ b1l,
                                                 float* __restrict__ base1) {
  __shared__ __align__(16) unsigned short Bh[2][4096], Bl[2][4096];  // 32 KB
  __shared__ u64 lsurv[128 * 20];                                    // 20 KB
  __shared__ int lcnt[128];
  const int t = threadIdx.x;
  const int bg = blockIdx.x / 96;
  const int rem = blockIdx.x % 96;
  const int qg = rem / 4, cq = rem % 4;
  const int w = t >> 6, lane = t & 63;
  const int lane16 = lane & 15, quad = lane >> 4;
  const float* xxb = xx + (size_t)bg * NN;
  const int rowbase = bg * NN + qg * 128 + w * 32;  // + mt*16 + quad*4 + r

  short8 afh[2][2], afl[2][2];
  {
    const size_t base = ((size_t)bg * 24 + qg) * 8192;
#pragma unroll
    for (int mt = 0; mt < 2; ++mt)
#pragma unroll
      for (int kc = 0; kc < 2; ++kc) {
        const size_t off = base + (size_t)(w * 2 + mt) * 1024 + kc * 512 + lane * 8;
        afh[mt][kc] = *(const short8*)(hhi + off);
        afl[mt][kc] = *(const short8*)(hlo + off);
      }
  }
  float Tr[2][4];
#pragma unroll
  for (int mt = 0; mt < 2; ++mt)
#pragma unroll
    for (int r = 0; r < 4; ++r) Tr[mt][r] = T[rowbase + mt * 16 + quad * 4 + r];
  if (t < 128) lcnt[t] = 0;

  STAGE(cq * 12, 0);
  __syncthreads();
  for (int it = 0; it < 12; ++it) {
    const int cb = cq * 12 + it;
    if (it + 1 < 12) STAGE(cb + 1, (it + 1) & 1);
    const unsigned short* bhp = Bh[it & 1];
    const unsigned short* blp = Bl[it & 1];
    f32x4 acc[2][4];
#pragma unroll
    for (int mt = 0; mt < 2; ++mt)
#pragma unroll
      for (int nt = 0; nt < 4; ++nt) acc[mt][nt] = (f32x4){0.f, 0.f, 0.f, 0.f};
#pragma unroll
    for (int kc = 0; kc < 2; ++kc)
#pragma unroll
      for (int nt = 0; nt < 4; ++nt) {
        const int off = nt * 1024 + kc * 512 + lane * 8;
        const short8 bh = *(const short8*)&bhp[off];
        const short8 bl = *(const short8*)&blp[off];
#pragma unroll
        for (int mt = 0; mt < 2; ++mt) {
          acc[mt][nt] = __builtin_amdgcn_mfma_f32_16x16x32_bf16(afh[mt][kc], bh, acc[mt][nt], 0, 0, 0);
          acc[mt][nt] = __builtin_amdgcn_mfma_f32_16x16x32_bf16(afh[mt][kc], bl, acc[mt][nt], 0, 0, 0);
          acc[mt][nt] = __builtin_amdgcn_mfma_f32_16x16x32_bf16(afl[mt][kc], bh, acc[mt][nt], 0, 0, 0);
        }
      }
#pragma unroll
    for (int nt = 0; nt < 4; ++nt) {
      const float xc = xxb[cb * 64 + nt * 16 + lane16];
#pragma unroll
      for (int mt = 0; mt < 2; ++mt)
#pragma unroll
        for (int r = 0; r < 4; ++r) {
          const float d = fmaf(-2.0f, acc[mt][nt][r], xc);
          if (d <= Tr[mt][r]) {
            const int rloc = w * 32 + mt * 16 + quad * 4 + r;
            const int idx = atomicAdd(&lcnt[rloc], 1);  // LDS atomic: fast
            if (idx < 20)
              lsurv[rloc * 20 + idx] =
                  ((u64)sortkey(d) << 32) | (unsigned)(cb * 64 + nt * 16 + lane16);
          }
        }
    }
    __syncthreads();  // drains prefetch vmcnt + syncs buffer reuse
  }
#undef STAGE
  // merge: one independent global atomic per row (parallel across 128 threads)
  if (t < 128) {
    const int row = bg * NN + qg * 128 + t;
    int myc = lcnt[t];
    myc = myc > 20 ? 20 : myc;
    const int base = atomicAdd(&cnt[row], myc);
    for (int i = 0; i < myc; ++i) {
      const int pos = base + i;
      if (pos < 96) surv[(size_t)row * 96 + pos] = lsurv[t * 20 + i];
    }
  }
  // cq==0 epilogue: base1 for this block's 128 rows (bit-identical to k_base)
  if (cq == 0) {
    f32x4 accB[2][8];
#pragma unroll
    for (int mt = 0; mt < 2; ++mt)
#pragma unroll
      for (int nt = 0; nt < 8; ++nt) {
        const float bv = b1l[nt * 16 + lane16];
        accB[mt][nt] = (f32x4){bv, bv, bv, bv};
      }
#pragma unroll
    for (int kc = 0; kc < 2; ++kc)
#pragma unroll
      for (int mt = 0; mt < 2; ++mt) {
        const short8 ah = afh[mt][kc];
        const short8 al = afl[mt][kc];
#pragma unroll
        for (int nt = 0; nt < 8; ++nt) {
          const int offB = ((nt * 2 + kc) * 64 + lane) * 8;
          const short8 bh = *(const short8*)(w0h + offB);
          const short8 bl = *(const short8*)(w0l + offB);
          accB[mt][nt] = __builtin_amdgcn_mfma_f32_16x16x32_bf16(ah, bh, accB[mt][nt], 0, 0, 0);
          accB[mt][nt] = __builtin_amdgcn_mfma_f32_16x16x32_bf16(ah, bl, accB[mt][nt], 0, 0, 0);
          accB[mt][nt] = __builtin_amdgcn_mfma_f32_16x16x32_bf16(al, bh, accB[mt][nt], 0, 0, 0);
        }
      }
    const int grp = bg * 24 + qg;
#pragma unroll
    for (int mt = 0; mt < 2; ++mt)
#pragma unroll
      for (int nt = 0; nt < 8; ++nt) {
        const int row = (w * 2 + mt) * 16 + quad * 4;
        const int col = nt * 16 + lane16;
#pragma unroll
        for (int r = 0; r < 4; ++r)
          base1[((size_t)grp * 128 + row + r) * 128 + col] = accB[mt][nt][r];
      }
  }
}

// -------- edge MLP + fused rank, bf16 MFMA: 4 points (64 edges) per block --------
__global__ __launch_bounds__(256, 4) void k_msg3(
    const float* __restrict__ h, const int* __restrict__ cnt,
    const u64* __restrict__ surv,
    const float* __restrict__ base1, const float* __restrict__ b2l,
    const unsigned short* __restrict__ w1h, const unsigned short* __restrict__ w2h,
    float* __restrict__ hout) {
  __shared__ unsigned short A1[4096];   // 8 KB: [p4][kc2][quad4][m16][8]
  __shared__ unsigned short m1b[8192];  // 16 KB: [w4][kc4][q2_4][m16][8]
  __shared__ float hloc[256];           // 1 KB
  __shared__ float base1L[512];         // 2 KB
  __shared__ u64 sbr[4][96];            // 3 KB
  __shared__ int knnL[4][16];           // 256 B
  const int t = threadIdx.x;
  const int b = blockIdx.x / (NN / 4);
  const int p0 = (blockIdx.x % (NN / 4)) * 4;
  const float* hb = h + (size_t)b * NN * HD;
  const int w = t >> 6, lane = t & 63;
  const int lane16 = lane & 15, quad = lane >> 4;

  if (t < 64) {
    const int p = t >> 4, c4 = t & 15;
    *(float4*)&hloc[p * 64 + c4 * 4] = *(const float4*)(hb + (size_t)(p0 + p) * HD + c4 * 4);
  }
  if (t < 128)
    *(float4*)&base1L[t * 4] = *(const float4*)(base1 + ((size_t)b * NN + p0) * 128 + t * 4);

  // fused rank: wave w ranks flat row b*NN + p0 + w (bit-identical to k_rank)
  {
    const int row = b * NN + p0 + w;
    if (lane < 16) knnL[w][lane] = 0;  // safety vs cap-truncation tail
    int c = cnt[row];
    c = c > 96 ? 96 : c;
    const u64 m0 = (lane < c) ? surv[(size_t)row * 96 + lane] : ~0ull;
    const u64 m1 = (64 + lane < c) ? surv[(size_t)row * 96 + 64 + lane] : ~0ull;
    sbr[w][lane] = m0;  // same-wave LDS: ordered
    if (lane < 32) sbr[w][64 + lane] = m1;
    int r0 = 0, r1 = 0;
    for (int i = 0; i < c; ++i) {
      const u64 sv = sbr[w][i];
      r0 += (sv < m0) ? 1 : 0;
      r1 += (sv < m1) ? 1 : 0;
    }
    if (lane < c && r0 < KK) knnL[w][r0] = (int)(unsigned)(m0 & 0xffffffffu);
    if (lane < 32 && 64 + lane < c && r1 < KK)
      knnL[w][r1] = (int)(unsigned)(m1 & 0xffffffffu);
  }
  __syncthreads();

  // gather diffs -> bf16 A-fragment order (packed cvt)
  {
    const int e = t >> 2, qs = t & 3;
    const int p = e >> 4, m = e & 15;
    const int j = knnL[p][m];
    const float* hj = hb + (size_t)j * HD + qs * 16;
    const int kc = qs >> 1;
#pragma unroll
    for (int half = 0; half < 2; ++half) {
      const int c0 = qs * 16 + half * 8;
      const int qd = (c0 >> 3) & 3;
      const float4 va = *(const float4*)(hj + half * 8);
      const float4 vb = *(const float4*)(hj + half * 8 + 4);
      const float4 ia = *(const float4*)&hloc[p * 64 + c0];
      const float4 ib = *(const float4*)&hloc[p * 64 + c0 + 4];
      uint4 o;
      o.x = pk2(va.x - ia.x, va.y - ia.y);
      o.y = pk2(va.z - ia.z, va.w - ia.w);
      o.z = pk2(vb.x - ib.x, vb.y - ib.y);
      o.w = pk2(vb.z - ib.z, vb.w - ib.w);
      *(uint4*)&A1[((p * 2 + kc) * 64 + qd * 16 + m) * 8] = o;
    }
  }
  __syncthreads();

  // GEMM1: 16 edges (point w) x 128 outs, K=64, bf16
  f32x4 acc1[8];
#pragma unroll
  for (int nt = 0; nt < 8; ++nt) {
    const float bv = base1L[w * 128 + nt * 16 + lane16];
    acc1[nt] = (f32x4){bv, bv, bv, bv};
  }
  short8 a1[2];
#pragma unroll
  for (int kc = 0; kc < 2; ++kc) a1[kc] = *(const short8*)&A1[((w * 2 + kc) * 64 + lane) * 8];
#pragma unroll
  for (int kc = 0; kc < 2; ++kc)
#pragma unroll
    for (int nt = 0; nt < 8; ++nt) {
      const short8 bh = *(const short8*)(w1h + ((nt * 2 + kc) * 64 + lane) * 8);
      acc1[nt] = __builtin_amdgcn_mfma_f32_16x16x32_bf16(a1[kc], bh, acc1[nt], 0, 0, 0);
    }
  // m1 -> elu -> bf16 (packed cvt) -> LDS in A-fragment order for GEMM2
#pragma unroll
  for (int nt = 0; nt < 8; ++nt) {
    const int c = nt * 16 + lane16;
    const int boff = w * 2048 + (c >> 5) * 512 + ((c >> 3) & 3) * 128 + (c & 7);
    const unsigned p01 = pk2(elu_f(acc1[nt][0]), elu_f(acc1[nt][1]));
    const unsigned p23 = pk2(elu_f(acc1[nt][2]), elu_f(acc1[nt][3]));
    m1b[boff + (quad * 4 + 0) * 8] = (unsigned short)p01;
    m1b[boff + (quad * 4 + 1) * 8] = (unsigned short)(p01 >> 16);
    m1b[boff + (quad * 4 + 2) * 8] = (unsigned short)p23;
    m1b[boff + (quad * 4 + 3) * 8] = (unsigned short)(p23 >> 16);
  }
  __syncthreads();

  // GEMM2: 16 edges x 64 outs, K=128, bf16
  f32x4 acc2[4];
#pragma unroll
  for (int nt = 0; nt < 4; ++nt) {
    const float bv = b2l[nt * 16 + lane16];
    acc2[nt] = (f32x4){bv, bv, bv, bv};
  }
#pragma unroll
  for (int kc = 0; kc < 4; ++kc) {
    const short8 a2 = *(const short8*)&m1b[w * 2048 + kc * 512 + quad * 128 + lane16 * 8];
#pragma unroll
    for (int nt = 0; nt < 4; ++nt) {
      const short8 bh = *(const short8*)(w2h + ((nt * 4 + kc) * 64 + lane) * 8);
      acc2[nt] = __builtin_amdgcn_mfma_f32_16x16x32_bf16(a2, bh, acc2[nt], 0, 0, 0);
    }
  }
  // epilogue: elu then sum over the 16 edges of point w
#pragma unroll
  for (int nt = 0; nt < 4; ++nt) {
    float s = elu_f(acc2[nt][0]) + elu_f(acc2[nt][1]) + elu_f(acc2[nt][2]) + elu_f(acc2[nt][3]);
    s += __shfl_xor(s, 16, 64);
    s += __shfl_xor(s, 32, 64);
    if (quad == 0) hout[((size_t)b * NN + p0 + w) * HD + nt * 16 + lane16] = s;
  }
}

// ---------------- parallel max-pool: 24 segments of 128 rows per batch -----------
__global__ void k_pool(const float* __restrict__ h, float* __restrict__ part) {
  __shared__ float red[4][64];
  const int t = threadIdx.x;
  const int gidx = blockIdx.x;  // 0..NB*24-1
  const int b = gidx / 24, seg = gidx % 24;
  const int q = t >> 6, d = t & 63;
  const float* hb = h + ((size_t)b * NN + seg * 128) * HD;
  float m = -3.402823466e+38f;
  for (int n = q; n < 128; n += 4) m = fmaxf(m, hb[(size_t)n * HD + d]);
  red[q][d] = m;
  __syncthreads();
  if (t < 64)
    part[(size_t)gidx * HD + t] =
        fmaxf(fmaxf(red[0][t], red[1][t]), fmaxf(red[2][t], red[3][t]));
}

// ---------------- final reduce + head MLP, one block per batch ----------------
__global__ void k_head2(const float* __restrict__ part, const float* __restrict__ Wo1,
                        const float* __restrict__ bo1, const float* __restrict__ Wo2,
                        const float* __restrict__ bo2, const float* __restrict__ Wo3,
                        const float* __restrict__ bo3, float* __restrict__ out) {
  __shared__ float pooled[64];
  __shared__ float o1[64];
  __shared__ float o2s[64];
  const int t = threadIdx.x;
  const int b = blockIdx.x;
  if (t < 64) {
    float m = -3.402823466e+38f;
    for (int g = 0; g < 24; ++g) m = fmaxf(m, part[((size_t)b * 24 + g) * HD + t]);
    pooled[t] = m;
  }
  __syncthreads();
  if (t < 64) {
    float a = bo1[t];
    for (int c = 0; c < 64; ++c) a = fmaf(pooled[c], Wo1[c * 64 + t], a);
    o1[t] = elu_f(a);
  }
  __syncthreads();
  if (t < 64) {
    float a = bo2[t];
    for (int c = 0; c < 64; ++c) a = fmaf(o1[c], Wo2[c * 64 + t], a);
    o2s[t] = elu_f(a);
  }
  __syncthreads();
  if (t < 64) {
    float v = o2s[t] * Wo3[t];
#pragma unroll
    for (int mm = 32; mm >= 1; mm >>= 1) v += __shfl_xor(v, mm, 64);
    if (t == 0) out[b] = v + bo3[0];
  }
}

extern "C" void kernel_launch(void* const* d_in, const int* in_sizes, int n_in,
                              void* d_out, int out_size, void* d_ws, size_t ws_size,
                              hipStream_t stream) {
  const float* x   = (const float*)d_in[0];
  const float* dn  = (const float*)d_in[1];
  const float* Win = (const float*)d_in[2];
  const float* bin = (const float*)d_in[3];
  const float* W1  = (const float*)d_in[4];
  const float* b1  = (const float*)d_in[5];
  const float* W2  = (const float*)d_in[6];
  const float* b2  = (const float*)d_in[7];
  const float* Wo1 = (const float*)d_in[8];
  const float* bo1 = (const float*)d_in[9];
  const float* Wo2 = (const float*)d_in[10];
  const float* bo2 = (const float*)d_in[11];
  const float* Wo3 = (const float*)d_in[12];
  const float* bo3 = (const float*)d_in[13];
  float* out = (float*)d_out;

  char* p = (char*)d_ws;
  const size_t hbytes = (size_t)NB * NN * HD * 4;  // 6291456
  float* h0 = (float*)p; p += hbytes;
  float* h1 = (float*)p; p += hbytes;
  float* xx = (float*)p; p += (size_t)NB * NN * 4;
  unsigned short* hhi = (unsigned short*)p; p += (size_t)NB * NN * HD * 2;
  unsigned short* hlo = (unsigned short*)p; p += (size_t)NB * NN * HD * 2;
  unsigned short* w0h = (unsigned short*)p; p += (size_t)NL * 8192 * 2;
  unsigned short* w0l = (unsigned short*)p; p += (size_t)NL * 8192 * 2;
  unsigned short* w1h = (unsigned short*)p; p += (size_t)NL * 8192 * 2;
  unsigned short* w2h = (unsigned short*)p; p += (size_t)NL * 8192 * 2;
  float* part = (float*)p; p += (size_t)NB * 24 * HD * 4;
  float* tilemin = (float*)p; p += (size_t)48 * ROWS_TOT * 4;   // 4.72 MB
  float* Tthr = (float*)p; p += (size_t)ROWS_TOT * 4;           // 98 KB
  int* scnt = (int*)p; p += (size_t)ROWS_TOT * 4;               // 98 KB
  u64* surv = (u64*)p; p += (size_t)ROWS_TOT * 96 * 8;          // 18.87 MB
  float* base1 = (float*)p; p += (size_t)NB * NN * 128 * 4;     // 12.58 MB
  // total ~55.5 MB

  const int rows = NB * NN;
  k_packw<<<NL * 3072 / 256, 256, 0, stream>>>(W1, W2, w0h, w0l, w1h, w2h);
  k_embed2<<<rows * HD / 8 / 256, 256, 0, stream>>>(x, dn, Win, bin, h0, hhi, hlo, xx);
  float* hin = h0;
  float* hbuf = h1;
  for (int l = 0; l < NL; ++l) {
    if (l > 0)
      k_split<<<rows * HD / 8 / 256, 256, 0, stream>>>(hin, hhi, hlo, xx);
    k_stat<<<NB * 96, 256, 0, stream>>>(hhi, hlo, xx, tilemin);
    k_thresh<<<rows / 4, 256, 0, stream>>>(tilemin, Tthr, scnt);
    k_compact<<<NB * 96, 256, 0, stream>>>(hhi, hlo, xx, Tthr, scnt, surv,
                                           w0h + (size_t)l * 8192, w0l + (size_t)l * 8192,
                                           b1 + l * 128, base1);
    k_msg3<<<rows / 4, 256, 0, stream>>>(hin, scnt, surv, base1, b2 + l * 64,
                                         w1h + (size_t)l * 8192, w2h + (size_t)l * 8192,
                                         hbuf);
    float* tmp = hin; hin = hbuf; hbuf = tmp;
  }
  k_pool<<<NB * 24, 256, 0, stream>>>(hin, part);
  k_head2<<<NB, 256, 0, stream>>>(part, Wo1, bo1, Wo2, bo2, Wo3, bo3, out);
}

// Round 20
// 381.944 us; speedup vs baseline: 1.1423x; 1.1423x over previous
//
#include <hip/hip_runtime.h>
#include <hip/hip_bf16.h>
#include <cstdint>

#define NB 8
#define NN 3072
#define HD 64
#define KK 16
#define NL 2
#define ROWS_TOT (NB * NN)

typedef unsigned long long u64;
typedef __attribute__((ext_vector_type(8))) short short8;
typedef __attribute__((ext_vector_type(4))) float f32x4;

__device__ __forceinline__ float elu_f(float x) {
  return x > 0.0f ? x : __expf(x) - 1.0f;  // v_exp-based; abs err ~1e-7
}

__device__ __forceinline__ unsigned sortkey(float f) {
  unsigned u = __float_as_uint(f);
  unsigned m = ((unsigned)((int)u >> 31)) | 0x80000000u;
  return u ^ m;  // monotone float->uint map
}

// packed RNE f32->bf16 pair: returns lo16 = bf16(a), hi16 = bf16(b).
__device__ __forceinline__ unsigned pk2(float a, float b) {
  __hip_bfloat162 v = __float22bfloat162_rn(make_float2(a, b));
  return *(unsigned*)&v;
}

__device__ __forceinline__ unsigned short bf16rne(float f) {
  unsigned u = __float_as_uint(f);
  return (unsigned short)((u + 0x7fffu + ((u >> 16) & 1u)) >> 16);
}

// async global->LDS, 16B per lane; LDS dest must be wave-uniform base + lane*16
__device__ __forceinline__ void gl_lds16(const void* g, void* l) {
  __builtin_amdgcn_global_load_lds(
      (const __attribute__((address_space(1))) unsigned int*)g,
      (__attribute__((address_space(3))) unsigned int*)l, 16, 0, 0);
}

// ---- fused embed + split + norms (layer 0) ----
__global__ void k_embed2(const float* __restrict__ x, const float* __restrict__ dn,
                         const float* __restrict__ Win, const float* __restrict__ bin,
                         float* __restrict__ h, unsigned short* __restrict__ hhi,
                         unsigned short* __restrict__ hlo, float* __restrict__ xx) {
  __shared__ float xsum[32];
  const int t = threadIdx.x;
  const int C = blockIdx.x * 256 + t;  // one 8-elem chunk per thread
  const int Rg = C >> 10;
  const int within = C & 1023;
  const int rt16 = within >> 7;
  const int kc = (within >> 6) & 1;
  const int quad = (within >> 4) & 3;
  const int row = within & 15;
  const int lr = ((t >> 7) & 1) * 16 + (t & 15);  // local row 0..31
  const int r = Rg * 128 + rt16 * 16 + row;
  const int k0 = kc * 32 + quad * 8;
  if (t < 32) xsum[t] = 0.0f;
  __syncthreads();
  const float xd0 = x[(size_t)r * 3 + 0] * dn[0];
  const float xd1 = x[(size_t)r * 3 + 1] * dn[1];
  const float xd2 = x[(size_t)r * 3 + 2] * dn[2];
  float hv[8];
  float ss = 0.0f;
#pragma unroll
  for (int j = 0; j < 8; ++j) {
    const int d = k0 + j;
    float a = bin[d];
    a = fmaf(xd0, Win[d], a);
    a = fmaf(xd1, Win[HD + d], a);
    a = fmaf(xd2, Win[2 * HD + d], a);
    const float f = elu_f(a);
    hv[j] = f;
    ss = fmaf(f, f, ss);
  }
  atomicAdd(&xsum[lr], ss);
  *(float4*)(h + (size_t)r * HD + k0) = (float4){hv[0], hv[1], hv[2], hv[3]};
  *(float4*)(h + (size_t)r * HD + k0 + 4) = (float4){hv[4], hv[5], hv[6], hv[7]};
  uint4 oh, ol;
  unsigned* ohv = (unsigned*)&oh;
  unsigned* olv = (unsigned*)&ol;
#pragma unroll
  for (int jp = 0; jp < 4; ++jp) {
    const float f0 = hv[2 * jp], f1 = hv[2 * jp + 1];
    const unsigned hi = pk2(f0, f1);
    ohv[jp] = hi;
    const float hif0 = __uint_as_float(hi << 16);
    const float hif1 = __uint_as_float(hi & 0xffff0000u);
    olv[jp] = pk2(f0 - hif0, f1 - hif1);
  }
  *(uint4*)(hhi + (size_t)C * 8) = oh;
  *(uint4*)(hlo + (size_t)C * 8) = ol;
  __syncthreads();
  if (((t >> 4) & 7) == 0) xx[r] = xsum[lr];
}

// ------- split h (fp32) -> bf16 hi/lo in MFMA fragment order; fused row norms ----
__global__ void k_split(const float* __restrict__ h, unsigned short* __restrict__ hhi,
                        unsigned short* __restrict__ hlo, float* __restrict__ xx) {
  __shared__ float xsum[32];
  const int t = threadIdx.x;
  const int C = blockIdx.x * 256 + t;  // one 8-elem chunk per thread
  const int Rg = C >> 10;              // 128-row block index
  const int within = C & 1023;
  const int rt16 = within >> 7;
  const int kc = (within >> 6) & 1;
  const int quad = (within >> 4) & 3;
  const int row = within & 15;
  const int lr = ((t >> 7) & 1) * 16 + (t & 15);  // local row 0..31
  const int r = Rg * 128 + rt16 * 16 + row;
  const int k0 = kc * 32 + quad * 8;
  const float* src = h + (size_t)r * HD + k0;
  if (t < 32) xsum[t] = 0.0f;
  __syncthreads();
  const float4 v0 = *(const float4*)src;
  const float4 v1 = *(const float4*)(src + 4);
  const float fv[8] = {v0.x, v0.y, v0.z, v0.w, v1.x, v1.y, v1.z, v1.w};
  float ss = 0.0f;
#pragma unroll
  for (int j = 0; j < 8; ++j) ss = fmaf(fv[j], fv[j], ss);
  atomicAdd(&xsum[lr], ss);
  uint4 oh, ol;
  unsigned* ohv = (unsigned*)&oh;
  unsigned* olv = (unsigned*)&ol;
#pragma unroll
  for (int jp = 0; jp < 4; ++jp) {
    const float f0 = fv[2 * jp], f1 = fv[2 * jp + 1];
    const unsigned hi = pk2(f0, f1);
    ohv[jp] = hi;
    const float hif0 = __uint_as_float(hi << 16);
    const float hif1 = __uint_as_float(hi & 0xffff0000u);
    olv[jp] = pk2(f0 - hif0, f1 - hif1);
  }
  *(uint4*)(hhi + (size_t)C * 8) = oh;
  *(uint4*)(hlo + (size_t)C * 8) = ol;
  __syncthreads();
  if (((t >> 4) & 7) == 0) xx[r] = xsum[lr];  // kc==0 && quad==0: 32 writers
}

// ---- pack weights into MFMA B-fragment order: W1[0:64] hi+lo, W1[64:128] hi, W2 hi
__global__ void k_packw(const float* __restrict__ W1, const float* __restrict__ W2,
                        unsigned short* __restrict__ w0h, unsigned short* __restrict__ w0l,
                        unsigned short* __restrict__ w1h, unsigned short* __restrict__ w2h) {
  const int cid = blockIdx.x * 256 + threadIdx.x;  // 6144 chunks
  const int l = cid / 3072;
  const int r = cid % 3072;
  const int lane = r & 63;
  if (r < 1024) {  // W1 base part (K=0..63), hi+lo
    const int c = r;
    const int nt = c >> 7, kc = (c >> 6) & 1;
    const int k0 = kc * 32 + (lane >> 4) * 8;
    const int n = nt * 16 + (lane & 15);
    unsigned short* dh = w0h + ((size_t)l * 1024 + c) * 8;
    unsigned short* dl = w0l + ((size_t)l * 1024 + c) * 8;
#pragma unroll
    for (int j = 0; j < 8; ++j) {
      const float f = W1[(size_t)l * 16384 + (k0 + j) * 128 + n];
      const unsigned short hb = bf16rne(f);
      const float lo = f - __uint_as_float((unsigned)hb << 16);
      dh[j] = hb;
      dl[j] = bf16rne(lo);
    }
  } else if (r < 2048) {  // W1 diff part (K=64..127), hi only
    const int c = r - 1024;
    const int nt = c >> 7, kc = (c >> 6) & 1;
    const int k0 = 64 + kc * 32 + (lane >> 4) * 8;
    const int n = nt * 16 + (lane & 15);
    unsigned short* dh = w1h + ((size_t)l * 1024 + c) * 8;
#pragma unroll
    for (int j = 0; j < 8; ++j) dh[j] = bf16rne(W1[(size_t)l * 16384 + (k0 + j) * 128 + n]);
  } else {  // W2, hi only
    const int c = r - 2048;
    const int nt = c >> 8, kc = (c >> 6) & 3;
    const int k0 = kc * 32 + (lane >> 4) * 8;
    const int n = nt * 16 + (lane & 15);
    unsigned short* dh = w2h + ((size_t)l * 1024 + c) * 8;
#pragma unroll
    for (int j = 0; j < 8; ++j) dh[j] = bf16rne(W2[(size_t)l * 8192 + (k0 + j) * 64 + n]);
  }
}

// ---------------- KNN stage A: per-(tile,row) min of d2' -------------------------
__global__ __launch_bounds__(256) void k_stat(const unsigned short* __restrict__ hhi,
                                              const unsigned short* __restrict__ hlo,
                                              const float* __restrict__ xx,
                                              float* __restrict__ tilemin) {
  __shared__ __align__(16) unsigned short Bh[2][4096], Bl[2][4096];  // 32 KB
  __shared__ float smin[128 * 13];                                   // 6.7 KB
  const int t = threadIdx.x;
  const int bg = blockIdx.x / 96;
  const int rem = blockIdx.x % 96;
  const int qg = rem / 4, cq = rem % 4;
  const int w = t >> 6, lane = t & 63;
  const int lane16 = lane & 15, quad = lane >> 4;
  const float* xxb = xx + (size_t)bg * NN;

  short8 afh[2][2], afl[2][2];  // 2 mt x 2 kc; rows qg*128 + w*32 + mt*16 + ...
  {
    const size_t base = ((size_t)bg * 24 + qg) * 8192;
#pragma unroll
    for (int mt = 0; mt < 2; ++mt)
#pragma unroll
      for (int kc = 0; kc < 2; ++kc) {
        const size_t off = base + (size_t)(w * 2 + mt) * 1024 + kc * 512 + lane * 8;
        afh[mt][kc] = *(const short8*)(hhi + off);
        afl[mt][kc] = *(const short8*)(hlo + off);
      }
  }
#define STAGE(cb, bsel)                                                       \
  {                                                                           \
    const size_t bb = ((size_t)bg * 24 + ((cb) >> 1)) * 8192 +                \
                      (size_t)((cb) & 1) * 4096;                              \
    const char* sH = (const char*)(hhi + bb);                                 \
    const char* sL = (const char*)(hlo + bb);                                 \
    char* dH = (char*)&Bh[bsel][0];                                           \
    char* dL = (char*)&Bl[bsel][0];                                           \
    const int o1 = t * 16, o2 = t * 16 + 4096;                                \
    gl_lds16(sH + o1, dH + o1);                                               \
    gl_lds16(sH + o2, dH + o2);                                               \
    gl_lds16(sL + o1, dL + o1);                                               \
    gl_lds16(sL + o2, dL + o2);                                               \
  }

  STAGE(cq * 12, 0);
  __syncthreads();
  for (int it = 0; it < 12; ++it) {
    const int cb = cq * 12 + it;
    if (it + 1 < 12) STAGE(cb + 1, (it + 1) & 1);
    const unsigned short* bhp = Bh[it & 1];
    const unsigned short* blp = Bl[it & 1];
    f32x4 acc[2][4];
#pragma unroll
    for (int mt = 0; mt < 2; ++mt)
#pragma unroll
      for (int nt = 0; nt < 4; ++nt) acc[mt][nt] = (f32x4){0.f, 0.f, 0.f, 0.f};
#pragma unroll
    for (int kc = 0; kc < 2; ++kc)
#pragma unroll
      for (int nt = 0; nt < 4; ++nt) {
        const int off = nt * 1024 + kc * 512 + lane * 8;
        const short8 bh = *(const short8*)&bhp[off];
        const short8 bl = *(const short8*)&blp[off];
#pragma unroll
        for (int mt = 0; mt < 2; ++mt) {
          acc[mt][nt] = __builtin_amdgcn_mfma_f32_16x16x32_bf16(afh[mt][kc], bh, acc[mt][nt], 0, 0, 0);
          acc[mt][nt] = __builtin_amdgcn_mfma_f32_16x16x32_bf16(afh[mt][kc], bl, acc[mt][nt], 0, 0, 0);
          acc[mt][nt] = __builtin_amdgcn_mfma_f32_16x16x32_bf16(afl[mt][kc], bh, acc[mt][nt], 0, 0, 0);
        }
      }
    float rm[2][4];
#pragma unroll
    for (int mt = 0; mt < 2; ++mt)
#pragma unroll
      for (int r = 0; r < 4; ++r) rm[mt][r] = 3.402823466e+38f;
#pragma unroll
    for (int nt = 0; nt < 4; ++nt) {
      const float xc = xxb[cb * 64 + nt * 16 + lane16];
#pragma unroll
      for (int mt = 0; mt < 2; ++mt)
#pragma unroll
        for (int r = 0; r < 4; ++r)
          rm[mt][r] = fminf(rm[mt][r], fmaf(-2.0f, acc[mt][nt][r], xc));
    }
#pragma unroll
    for (int mask = 1; mask <= 8; mask <<= 1)
#pragma unroll
      for (int mt = 0; mt < 2; ++mt)
#pragma unroll
        for (int r = 0; r < 4; ++r)
          rm[mt][r] = fminf(rm[mt][r], __shfl_xor(rm[mt][r], mask, 64));
#pragma unroll
    for (int mt = 0; mt < 2; ++mt) {
      float v = rm[mt][0];
      v = (lane16 == 1) ? rm[mt][1] : v;
      v = (lane16 == 2) ? rm[mt][2] : v;
      v = (lane16 == 3) ? rm[mt][3] : v;
      if (lane16 < 4) {
        const int row = w * 32 + mt * 16 + quad * 4 + lane16;
        smin[row * 13 + it] = v;
      }
    }
    __syncthreads();  // drains prefetch vmcnt + syncs buffer reuse
  }
  // coalesced write: each of 128 rows writes its 12 contiguous floats
  if (t < 128) {
    float* dst = tilemin + ((size_t)bg * NN + qg * 128 + t) * 48 + cq * 12;
    const float* src = &smin[t * 13];
    *(float4*)dst = (float4){src[0], src[1], src[2], src[3]};
    *(float4*)(dst + 4) = (float4){src[4], src[5], src[6], src[7]};
    *(float4*)(dst + 8) = (float4){src[8], src[9], src[10], src[11]};
  }
}

// ---------------- KNN stage B: T[row] = 16th-smallest of 48 tile-mins ------------
__global__ __launch_bounds__(256) void k_thresh(const float* __restrict__ tilemin,
                                                float* __restrict__ T,
                                                int* __restrict__ cnt) {
  __shared__ float sb[4][64];
  const int t = threadIdx.x, w = t >> 6, lane = t & 63;
  const int row = blockIdx.x * 4 + w;
  const float v = (lane < 48) ? tilemin[(size_t)row * 48 + lane] : 3.402823466e+38f;
  sb[w][lane] = v;  // same-wave LDS: ordered
  int rank = 0;
  for (int i = 0; i < 48; ++i) {
    const float s = sb[w][i];
    rank += (s < v) || (s == v && i < lane);
  }
  if (lane < 48 && rank == 15) T[row] = v;
  if (lane == 0) cnt[row] = 0;
}

// ---------------- KNN stage C: recompute (bit-identical), LDS-compact survivors --
__global__ __launch_bounds__(256) void k_compact(const unsigned short* __restrict__ hhi,
                                                 const unsigned short* __restrict__ hlo,
                                                 const float* __restrict__ xx,
                                                 const float* __restrict__ T,
                                                 int* __restrict__ cnt,
                                                 u64* __restrict__ surv) {
  __shared__ __align__(16) unsigned short Bh[2][4096], Bl[2][4096];  // 32 KB
  __shared__ u64 lsurv[128 * 20];                                    // 20 KB
  __shared__ int lcnt[128];
  const int t = threadIdx.x;
  const int bg = blockIdx.x / 96;
  const int rem = blockIdx.x % 96;
  const int qg = rem / 4, cq = rem % 4;
  const int w = t >> 6, lane = t & 63;
  const int lane16 = lane & 15, quad = lane >> 4;
  const float* xxb = xx + (size_t)bg * NN;
  const int rowbase = bg * NN + qg * 128 + w * 32;  // + mt*16 + quad*4 + r

  short8 afh[2][2], afl[2][2];
  {
    const size_t base = ((size_t)bg * 24 + qg) * 8192;
#pragma unroll
    for (int mt = 0; mt < 2; ++mt)
#pragma unroll
      for (int kc = 0; kc < 2; ++kc) {
        const size_t off = base + (size_t)(w * 2 + mt) * 1024 + kc * 512 + lane * 8;
        afh[mt][kc] = *(const short8*)(hhi + off);
        afl[mt][kc] = *(const short8*)(hlo + off);
      }
  }
  float Tr[2][4];
#pragma unroll
  for (int mt = 0; mt < 2; ++mt)
#pragma unroll
    for (int r = 0; r < 4; ++r) Tr[mt][r] = T[rowbase + mt * 16 + quad * 4 + r];
  if (t < 128) lcnt[t] = 0;

  STAGE(cq * 12, 0);
  __syncthreads();
  for (int it = 0; it < 12; ++it) {
    const int cb = cq * 12 + it;
    if (it + 1 < 12) STAGE(cb + 1, (it + 1) & 1);
    const unsigned short* bhp = Bh[it & 1];
    const unsigned short* blp = Bl[it & 1];
    f32x4 acc[2][4];
#pragma unroll
    for (int mt = 0; mt < 2; ++mt)
#pragma unroll
      for (int nt = 0; nt < 4; ++nt) acc[mt][nt] = (f32x4){0.f, 0.f, 0.f, 0.f};
#pragma unroll
    for (int kc = 0; kc < 2; ++kc)
#pragma unroll
      for (int nt = 0; nt < 4; ++nt) {
        const int off = nt * 1024 + kc * 512 + lane * 8;
        const short8 bh = *(const short8*)&bhp[off];
        const short8 bl = *(const short8*)&blp[off];
#pragma unroll
        for (int mt = 0; mt < 2; ++mt) {
          acc[mt][nt] = __builtin_amdgcn_mfma_f32_16x16x32_bf16(afh[mt][kc], bh, acc[mt][nt], 0, 0, 0);
          acc[mt][nt] = __builtin_amdgcn_mfma_f32_16x16x32_bf16(afh[mt][kc], bl, acc[mt][nt], 0, 0, 0);
          acc[mt][nt] = __builtin_amdgcn_mfma_f32_16x16x32_bf16(afl[mt][kc], bh, acc[mt][nt], 0, 0, 0);
        }
      }
#pragma unroll
    for (int nt = 0; nt < 4; ++nt) {
      const float xc = xxb[cb * 64 + nt * 16 + lane16];
#pragma unroll
      for (int mt = 0; mt < 2; ++mt)
#pragma unroll
        for (int r = 0; r < 4; ++r) {
          const float d = fmaf(-2.0f, acc[mt][nt][r], xc);
          if (d <= Tr[mt][r]) {
            const int rloc = w * 32 + mt * 16 + quad * 4 + r;
            const int idx = atomicAdd(&lcnt[rloc], 1);  // LDS atomic: fast
            if (idx < 20)
              lsurv[rloc * 20 + idx] =
                  ((u64)sortkey(d) << 32) | (unsigned)(cb * 64 + nt * 16 + lane16);
          }
        }
    }
    __syncthreads();  // drains prefetch vmcnt + syncs buffer reuse
  }
#undef STAGE
  // merge: one independent global atomic per row (parallel across 128 threads)
  if (t < 128) {
    const int row = bg * NN + qg * 128 + t;
    int myc = lcnt[t];
    myc = myc > 20 ? 20 : myc;
    const int base = atomicAdd(&cnt[row], myc);
    for (int i = 0; i < myc; ++i) {
      const int pos = base + i;
      if (pos < 96) surv[(size_t)row * 96 + pos] = lsurv[t * 20 + i];
    }
  }
}

// ---------------- base1 = h @ W1[0:64] + b1 (split-bf16 MFMA, near-fp32) ---------
__global__ __launch_bounds__(256, 2) void k_base(const unsigned short* __restrict__ hhi,
                                                 const unsigned short* __restrict__ hlo,
                                                 const unsigned short* __restrict__ w0h,
                                                 const unsigned short* __restrict__ w0l,
                                                 const float* __restrict__ b1l,
                                                 float* __restrict__ base1) {
  __shared__ unsigned short Ah[8192], Al[8192];  // 32 KB
  const int t = threadIdx.x;
  const int grp = blockIdx.x;  // 0..191: global 128-row group
  {
    const uint4* sah = (const uint4*)(hhi + (size_t)grp * 8192);
    const uint4* sal = (const uint4*)(hlo + (size_t)grp * 8192);
#pragma unroll
    for (int i = 0; i < 4; ++i) {
      ((uint4*)Ah)[t + 256 * i] = sah[t + 256 * i];
      ((uint4*)Al)[t + 256 * i] = sal[t + 256 * i];
    }
  }
  __syncthreads();
  const int w = t >> 6, lane = t & 63;
  const int lane16 = lane & 15, quad = lane >> 4;
  f32x4 acc[2][8];
#pragma unroll
  for (int mt = 0; mt < 2; ++mt)
#pragma unroll
    for (int nt = 0; nt < 8; ++nt) {
      const float bv = b1l[nt * 16 + lane16];
      acc[mt][nt] = (f32x4){bv, bv, bv, bv};
    }
#pragma unroll
  for (int kc = 0; kc < 2; ++kc)
#pragma unroll
    for (int mt = 0; mt < 2; ++mt) {
      const int offA = (((w * 2 + mt) * 2 + kc) * 64 + lane) * 8;
      const short8 ah = *(const short8*)&Ah[offA];
      const short8 al = *(const short8*)&Al[offA];
#pragma unroll
      for (int nt = 0; nt < 8; ++nt) {
        const int offB = ((nt * 2 + kc) * 64 + lane) * 8;
        const short8 bh = *(const short8*)(w0h + offB);
        const short8 bl = *(const short8*)(w0l + offB);
        acc[mt][nt] = __builtin_amdgcn_mfma_f32_16x16x32_bf16(ah, bh, acc[mt][nt], 0, 0, 0);
        acc[mt][nt] = __builtin_amdgcn_mfma_f32_16x16x32_bf16(ah, bl, acc[mt][nt], 0, 0, 0);
        acc[mt][nt] = __builtin_amdgcn_mfma_f32_16x16x32_bf16(al, bh, acc[mt][nt], 0, 0, 0);
      }
    }
#pragma unroll
  for (int mt = 0; mt < 2; ++mt)
#pragma unroll
    for (int nt = 0; nt < 8; ++nt) {
      const int row = (w * 2 + mt) * 16 + quad * 4;
      const int col = nt * 16 + lane16;
#pragma unroll
      for (int r = 0; r < 4; ++r)
        base1[((size_t)grp * 128 + row + r) * 128 + col] = acc[mt][nt][r];
    }
}

// -------- edge MLP + fused rank, bf16 MFMA: 4 points (64 edges) per block --------
__global__ __launch_bounds__(256, 4) void k_msg3(
    const float* __restrict__ h, const int* __restrict__ cnt,
    const u64* __restrict__ surv,
    const float* __restrict__ base1, const float* __restrict__ b2l,
    const unsigned short* __restrict__ w1h, const unsigned short* __restrict__ w2h,
    float* __restrict__ hout) {
  __shared__ unsigned short A1[4096];   // 8 KB: [p4][kc2][quad4][m16][8]
  __shared__ unsigned short m1b[8192];  // 16 KB: [w4][kc4][q2_4][m16][8]
  __shared__ float hloc[256];           // 1 KB
  __shared__ float base1L[512];         // 2 KB
  __shared__ u64 sbr[4][96];            // 3 KB
  __shared__ int knnL[4][16];           // 256 B
  const int t = threadIdx.x;
  const int b = blockIdx.x / (NN / 4);
  const int p0 = (blockIdx.x % (NN / 4)) * 4;
  const float* hb = h + (size_t)b * NN * HD;
  const int w = t >> 6, lane = t & 63;
  const int lane16 = lane & 15, quad = lane >> 4;

  if (t < 64) {
    const int p = t >> 4, c4 = t & 15;
    *(float4*)&hloc[p * 64 + c4 * 4] = *(const float4*)(hb + (size_t)(p0 + p) * HD + c4 * 4);
  }
  if (t < 128)
    *(float4*)&base1L[t * 4] = *(const float4*)(base1 + ((size_t)b * NN + p0) * 128 + t * 4);

  // fused rank: wave w ranks flat row b*NN + p0 + w (bit-identical to k_rank)
  {
    const int row = b * NN + p0 + w;
    if (lane < 16) knnL[w][lane] = 0;  // safety vs cap-truncation tail
    int c = cnt[row];
    c = c > 96 ? 96 : c;
    const u64 m0 = (lane < c) ? surv[(size_t)row * 96 + lane] : ~0ull;
    const u64 m1 = (64 + lane < c) ? surv[(size_t)row * 96 + 64 + lane] : ~0ull;
    sbr[w][lane] = m0;  // same-wave LDS: ordered
    if (lane < 32) sbr[w][64 + lane] = m1;
    int r0 = 0, r1 = 0;
    for (int i = 0; i < c; ++i) {
      const u64 sv = sbr[w][i];
      r0 += (sv < m0) ? 1 : 0;
      r1 += (sv < m1) ? 1 : 0;
    }
    if (lane < c && r0 < KK) knnL[w][r0] = (int)(unsigned)(m0 & 0xffffffffu);
    if (lane < 32 && 64 + lane < c && r1 < KK)
      knnL[w][r1] = (int)(unsigned)(m1 & 0xffffffffu);
  }
  __syncthreads();

  // gather diffs -> bf16 A-fragment order (packed cvt)
  {
    const int e = t >> 2, qs = t & 3;
    const int p = e >> 4, m = e & 15;
    const int j = knnL[p][m];
    const float* hj = hb + (size_t)j * HD + qs * 16;
    const int kc = qs >> 1;
#pragma unroll
    for (int half = 0; half < 2; ++half) {
      const int c0 = qs * 16 + half * 8;
      const int qd = (c0 >> 3) & 3;
      const float4 va = *(const float4*)(hj + half * 8);
      const float4 vb = *(const float4*)(hj + half * 8 + 4);
      const float4 ia = *(const float4*)&hloc[p * 64 + c0];
      const float4 ib = *(const float4*)&hloc[p * 64 + c0 + 4];
      uint4 o;
      o.x = pk2(va.x - ia.x, va.y - ia.y);
      o.y = pk2(va.z - ia.z, va.w - ia.w);
      o.z = pk2(vb.x - ib.x, vb.y - ib.y);
      o.w = pk2(vb.z - ib.z, vb.w - ib.w);
      *(uint4*)&A1[((p * 2 + kc) * 64 + qd * 16 + m) * 8] = o;
    }
  }
  __syncthreads();

  // GEMM1: 16 edges (point w) x 128 outs, K=64, bf16
  f32x4 acc1[8];
#pragma unroll
  for (int nt = 0; nt < 8; ++nt) {
    const float bv = base1L[w * 128 + nt * 16 + lane16];
    acc1[nt] = (f32x4){bv, bv, bv, bv};
  }
  short8 a1[2];
#pragma unroll
  for (int kc = 0; kc < 2; ++kc) a1[kc] = *(const short8*)&A1[((w * 2 + kc) * 64 + lane) * 8];
#pragma unroll
  for (int kc = 0; kc < 2; ++kc)
#pragma unroll
    for (int nt = 0; nt < 8; ++nt) {
      const short8 bh = *(const short8*)(w1h + ((nt * 2 + kc) * 64 + lane) * 8);
      acc1[nt] = __builtin_amdgcn_mfma_f32_16x16x32_bf16(a1[kc], bh, acc1[nt], 0, 0, 0);
    }
  // m1 -> elu -> bf16 (packed cvt) -> LDS in A-fragment order for GEMM2
#pragma unroll
  for (int nt = 0; nt < 8; ++nt) {
    const int c = nt * 16 + lane16;
    const int boff = w * 2048 + (c >> 5) * 512 + ((c >> 3) & 3) * 128 + (c & 7);
    const unsigned p01 = pk2(elu_f(acc1[nt][0]), elu_f(acc1[nt][1]));
    const unsigned p23 = pk2(elu_f(acc1[nt][2]), elu_f(acc1[nt][3]));
    m1b[boff + (quad * 4 + 0) * 8] = (unsigned short)p01;
    m1b[boff + (quad * 4 + 1) * 8] = (unsigned short)(p01 >> 16);
    m1b[boff + (quad * 4 + 2) * 8] = (unsigned short)p23;
    m1b[boff + (quad * 4 + 3) * 8] = (unsigned short)(p23 >> 16);
  }
  __syncthreads();

  // GEMM2: 16 edges x 64 outs, K=128, bf16
  f32x4 acc2[4];
#pragma unroll
  for (int nt = 0; nt < 4; ++nt) {
    const float bv = b2l[nt * 16 + lane16];
    acc2[nt] = (f32x4){bv, bv, bv, bv};
  }
#pragma unroll
  for (int kc = 0; kc < 4; ++kc) {
    const short8 a2 = *(const short8*)&m1b[w * 2048 + kc * 512 + quad * 128 + lane16 * 8];
#pragma unroll
    for (int nt = 0; nt < 4; ++nt) {
      const short8 bh = *(const short8*)(w2h + ((nt * 4 + kc) * 64 + lane) * 8);
      acc2[nt] = __builtin_amdgcn_mfma_f32_16x16x32_bf16(a2, bh, acc2[nt], 0, 0, 0);
    }
  }
  // epilogue: elu then sum over the 16 edges of point w
#pragma unroll
  for (int nt = 0; nt < 4; ++nt) {
    float s = elu_f(acc2[nt][0]) + elu_f(acc2[nt][1]) + elu_f(acc2[nt][2]) + elu_f(acc2[nt][3]);
    s += __shfl_xor(s, 16, 64);
    s += __shfl_xor(s, 32, 64);
    if (quad == 0) hout[((size_t)b * NN + p0 + w) * HD + nt * 16 + lane16] = s;
  }
}

// ---------------- parallel max-pool: 24 segments of 128 rows per batch -----------
__global__ void k_pool(const float* __restrict__ h, float* __restrict__ part) {
  __shared__ float red[4][64];
  const int t = threadIdx.x;
  const int gidx = blockIdx.x;  // 0..NB*24-1
  const int b = gidx / 24, seg = gidx % 24;
  const int q = t >> 6, d = t & 63;
  const float* hb = h + ((size_t)b * NN + seg * 128) * HD;
  float m = -3.402823466e+38f;
  for (int n = q; n < 128; n += 4) m = fmaxf(m, hb[(size_t)n * HD + d]);
  red[q][d] = m;
  __syncthreads();
  if (t < 64)
    part[(size_t)gidx * HD + t] =
        fmaxf(fmaxf(red[0][t], red[1][t]), fmaxf(red[2][t], red[3][t]));
}

// ---------------- final reduce + head MLP, one block per batch ----------------
__global__ void k_head2(const float* __restrict__ part, const float* __restrict__ Wo1,
                        const float* __restrict__ bo1, const float* __restrict__ Wo2,
                        const float* __restrict__ bo2, const float* __restrict__ Wo3,
                        const float* __restrict__ bo3, float* __restrict__ out) {
  __shared__ float pooled[64];
  __shared__ float o1[64];
  __shared__ float o2s[64];
  const int t = threadIdx.x;
  const int b = blockIdx.x;
  if (t < 64) {
    float m = -3.402823466e+38f;
    for (int g = 0; g < 24; ++g) m = fmaxf(m, part[((size_t)b * 24 + g) * HD + t]);
    pooled[t] = m;
  }
  __syncthreads();
  if (t < 64) {
    float a = bo1[t];
    for (int c = 0; c < 64; ++c) a = fmaf(pooled[c], Wo1[c * 64 + t], a);
    o1[t] = elu_f(a);
  }
  __syncthreads();
  if (t < 64) {
    float a = bo2[t];
    for (int c = 0; c < 64; ++c) a = fmaf(o1[c], Wo2[c * 64 + t], a);
    o2s[t] = elu_f(a);
  }
  __syncthreads();
  if (t < 64) {
    float v = o2s[t] * Wo3[t];
#pragma unroll
    for (int mm = 32; mm >= 1; mm >>= 1) v += __shfl_xor(v, mm, 64);
    if (t == 0) out[b] = v + bo3[0];
  }
}

extern "C" void kernel_launch(void* const* d_in, const int* in_sizes, int n_in,
                              void* d_out, int out_size, void* d_ws, size_t ws_size,
                              hipStream_t stream) {
  const float* x   = (const float*)d_in[0];
  const float* dn  = (const float*)d_in[1];
  const float* Win = (const float*)d_in[2];
  const float* bin = (const float*)d_in[3];
  const float* W1  = (const float*)d_in[4];
  const float* b1  = (const float*)d_in[5];
  const float* W2  = (const float*)d_in[6];
  const float* b2  = (const float*)d_in[7];
  const float* Wo1 = (const float*)d_in[8];
  const float* bo1 = (const float*)d_in[9];
  const float* Wo2 = (const float*)d_in[10];
  const float* bo2 = (const float*)d_in[11];
  const float* Wo3 = (const float*)d_in[12];
  const float* bo3 = (const float*)d_in[13];
  float* out = (float*)d_out;

  char* p = (char*)d_ws;
  const size_t hbytes = (size_t)NB * NN * HD * 4;  // 6291456
  float* h0 = (float*)p; p += hbytes;
  float* h1 = (float*)p; p += hbytes;
  float* xx = (float*)p; p += (size_t)NB * NN * 4;
  unsigned short* hhi = (unsigned short*)p; p += (size_t)NB * NN * HD * 2;
  unsigned short* hlo = (unsigned short*)p; p += (size_t)NB * NN * HD * 2;
  unsigned short* w0h = (unsigned short*)p; p += (size_t)NL * 8192 * 2;
  unsigned short* w0l = (unsigned short*)p; p += (size_t)NL * 8192 * 2;
  unsigned short* w1h = (unsigned short*)p; p += (size_t)NL * 8192 * 2;
  unsigned short* w2h = (unsigned short*)p; p += (size_t)NL * 8192 * 2;
  float* part = (float*)p; p += (size_t)NB * 24 * HD * 4;
  float* tilemin = (float*)p; p += (size_t)48 * ROWS_TOT * 4;   // 4.72 MB
  float* Tthr = (float*)p; p += (size_t)ROWS_TOT * 4;           // 98 KB
  int* scnt = (int*)p; p += (size_t)ROWS_TOT * 4;               // 98 KB
  u64* surv = (u64*)p; p += (size_t)ROWS_TOT * 96 * 8;          // 18.87 MB
  float* base1 = (float*)p; p += (size_t)NB * NN * 128 * 4;     // 12.58 MB
  // total ~55.5 MB

  const int rows = NB * NN;
  k_packw<<<NL * 3072 / 256, 256, 0, stream>>>(W1, W2, w0h, w0l, w1h, w2h);
  k_embed2<<<rows * HD / 8 / 256, 256, 0, stream>>>(x, dn, Win, bin, h0, hhi, hlo, xx);
  float* hin = h0;
  float* hbuf = h1;
  for (int l = 0; l < NL; ++l) {
    if (l > 0)
      k_split<<<rows * HD / 8 / 256, 256, 0, stream>>>(hin, hhi, hlo, xx);
    k_stat<<<NB * 96, 256, 0, stream>>>(hhi, hlo, xx, tilemin);
    k_thresh<<<rows / 4, 256, 0, stream>>>(tilemin, Tthr, scnt);
    k_compact<<<NB * 96, 256, 0, stream>>>(hhi, hlo, xx, Tthr, scnt, surv);
    k_base<<<rows / 128, 256, 0, stream>>>(hhi, hlo, w0h + (size_t)l * 8192,
                                           w0l + (size_t)l * 8192, b1 + l * 128, base1);
    k_msg3<<<rows / 4, 256, 0, stream>>>(hin, scnt, surv, base1, b2 + l * 64,
                                         w1h + (size_t)l * 8192, w2h + (size_t)l * 8192,
                                         hbuf);
    float* tmp = hin; hin = hbuf; hbuf = tmp;
  }
  k_pool<<<NB * 24, 256, 0, stream>>>(hin, part);
  k_head2<<<NB, 256, 0, stream>>>(part, Wo1, bo1, Wo2, bo2, Wo3, bo3, out);
}